// Round 6
// baseline (24.666 us; speedup 1.0000x reference)
//
#include <hip/hip_runtime.h>

typedef float v2f __attribute__((ext_vector_type(2)));

#define PI_OVER_4 0.78539816339744830962f

// ---- DPP lane permutes (VALU pipe) ----
#define DPP_XOR1  0xB1    // quad_perm [1,0,3,2]
#define DPP_XOR2  0x4E    // quad_perm [2,3,0,1]
#define DPP_XOR3  0x1B    // quad_perm [3,2,1,0]
#define DPP_XOR7  0x141   // row_half_mirror
#define DPP_XOR15 0x140   // row_mirror

template <int CTRL>
__device__ __forceinline__ float dppf(float v) {
    return __int_as_float(
        __builtin_amdgcn_update_dpp(0, __float_as_int(v), CTRL, 0xF, 0xF, true));
}
template <int CTRL>
__device__ __forceinline__ v2f dpp2(v2f v) {
    v2f r; r.x = dppf<CTRL>(v.x); r.y = dppf<CTRL>(v.y); return r;
}
__device__ __forceinline__ float xor4f(float v) { return dppf<DPP_XOR3>(dppf<DPP_XOR7>(v)); }
__device__ __forceinline__ float xor8f(float v) { return dppf<DPP_XOR7>(dppf<DPP_XOR15>(v)); }

// ---- explicit VOP3P packed fp32 (force v_pk_*; compiler was likely scalarizing) ----
__device__ __forceinline__ v2f pk_mul(v2f a, v2f b) {
    v2f d; asm("v_pk_mul_f32 %0, %1, %2" : "=v"(d) : "v"(a), "v"(b)); return d;
}
__device__ __forceinline__ v2f pk_add(v2f a, v2f b) {
    v2f d; asm("v_pk_add_f32 %0, %1, %2" : "=v"(d) : "v"(a), "v"(b)); return d;
}
__device__ __forceinline__ v2f pk_sub(v2f a, v2f b) {
    v2f d; asm("v_pk_add_f32 %0, %1, %2 neg_lo:[0,1] neg_hi:[0,1]" : "=v"(d) : "v"(a), "v"(b)); return d;
}
__device__ __forceinline__ v2f pk_fma(v2f a, v2f b, v2f c) {   // a*b + c
    v2f d; asm("v_pk_fma_f32 %0, %1, %2, %3" : "=v"(d) : "v"(a), "v"(b), "v"(c)); return d;
}
__device__ __forceinline__ v2f pk_fma_n(v2f a, v2f b, v2f c) { // -(a*b) + c
    v2f d; asm("v_pk_fma_f32 %0, %1, %2, %3 neg_lo:[1,0,0] neg_hi:[1,0,0]" : "=v"(d) : "v"(a), "v"(b), "v"(c)); return d;
}
__device__ __forceinline__ v2f pk_mul_bh(v2f a, v2f b) {       // (a.y,a.y) * b
    v2f d; asm("v_pk_mul_f32 %0, %1, %2 op_sel:[1,0] op_sel_hi:[1,1]" : "=v"(d) : "v"(a), "v"(b)); return d;
}
__device__ __forceinline__ v2f pk_fma_bl(v2f a, v2f b, v2f c) { // (a.x,a.x)*b + c
    v2f d; asm("v_pk_fma_f32 %0, %1, %2, %3 op_sel:[0,0,0] op_sel_hi:[0,1,1]" : "=v"(d) : "v"(a), "v"(b), "v"(c)); return d;
}

__device__ __forceinline__ float bperm(int addr, float v) {
    return __int_as_float(__builtin_amdgcn_ds_bpermute(addr, __float_as_int(v)));
}

// 16 lanes/sample. Pre-L1-ring coords t (s = P t); reg r bits (3..0) = (t4..t7).
// Lane bits u (recode): u3=t0, u2=t1, u1=t0^t2, u0=t1^t3.
// Cross-lane gate masks: g0&g7: lane^15 (g7 also r^1); g1: lane^7; g2: lane^3;
// g3: lane^1 & r^8. Reg gates g4,g5,g6: r^12, r^6, r^3.
// Roles: s0=par(u&11)^par(r&15), s1=par(u&12), s2=par(u&6), s3=pv,
// s4..s7 = pv^par(r&{8,12,14,15}); pv=par(u&3).   [verified round 5]
__global__ __launch_bounds__(256, 5) void qsim8_kernel(
        const float* __restrict__ x, const float* __restrict__ w,
        float* __restrict__ out, int nsamples) {
    const int tid = blockIdx.x * blockDim.x + threadIdx.x;
    const int sample = tid >> 4;
    if (sample >= nsamples) return;
    const int lane = threadIdx.x & 63;
    const int L = lane & 15;
    const int q8 = L & 7;

    // ---- per-lane transcendentals (2 sincos/lane) ----
    const float xq = x[(size_t)sample * 8 + q8];
    const float wA = (L < 8) ? w[2 * q8] : w[16 + 2 * q8];
    const float wB = w[2 * q8 + 1];
    const float Aang = fmaf(xq, PI_OVER_4, 0.5f * wA);
    const float Bang = 0.5f * wB;
    float sA_, cA_, sB_, cB_;
    __sincosf(Aang, &sA_, &cA_);
    __sincosf(Bang, &sB_, &cB_);
    const float v_chcz = cA_ * cB_, v_chsz = cA_ * sB_;
    const float v_shcz = sA_ * cB_, v_shsz = sA_ * sB_;

    // ---- distribute coefficients within the 16-lane group ----
    const int base = (lane & 48) << 2;
    float lf_chcz[4], lf_chsz[4], lf_shcz[4], lf_shsz[4];
    float ex_chcz[4], ex_chsz[4], ex_shcz[4], ex_shsz[4];
    float c2q[8], s2q[8];
#pragma unroll
    for (int q = 0; q < 4; ++q) {
        const int ad = base + 4 * q;
        lf_chcz[q] = bperm(ad, v_chcz); lf_chsz[q] = bperm(ad, v_chsz);
        lf_shcz[q] = bperm(ad, v_shcz); lf_shsz[q] = bperm(ad, v_shsz);
    }
#pragma unroll
    for (int q = 0; q < 4; ++q) {
        const int ad = base + 4 * (4 + q);
        ex_chcz[q] = bperm(ad, v_chcz); ex_chsz[q] = bperm(ad, v_chsz);
        ex_shcz[q] = bperm(ad, v_shcz); ex_shsz[q] = bperm(ad, v_shsz);
    }
#pragma unroll
    for (int q = 0; q < 8; ++q) {
        const int ad = base + 4 * (8 + q);
        c2q[q] = bperm(ad, cA_); s2q[q] = bperm(ad, sA_);
    }

    // ---- lane factor: qubits 0..3 selected by t-bits of this lane ----
    const int b0 = (L >> 3) & 1;
    const int b1 = (L >> 2) & 1;
    const int b2 = ((L >> 1) ^ (L >> 3)) & 1;
    const int b3 = (L ^ (L >> 2)) & 1;
    float Fr = b0 ? lf_shcz[0] : lf_chcz[0];
    float Fi = b0 ? lf_shsz[0] : -lf_chsz[0];
    {
        const float g1r = b1 ? lf_shcz[1] : lf_chcz[1];
        const float g1i = b1 ? lf_shsz[1] : -lf_chsz[1];
        const float tr = Fr * g1r - Fi * g1i;
        const float ti = Fr * g1i + Fi * g1r;
        const float g2r = b2 ? lf_shcz[2] : lf_chcz[2];
        const float g2i = b2 ? lf_shsz[2] : -lf_chsz[2];
        const float ur = tr * g2r - ti * g2i;
        const float ui = tr * g2i + ti * g2r;
        const float g3r = b3 ? lf_shcz[3] : lf_chcz[3];
        const float g3i = b3 ? lf_shsz[3] : -lf_chsz[3];
        Fr = ur * g3r - ui * g3i;
        Fi = ur * g3i + ui * g3r;
    }

    // ---- expand product state over qubits 4..7 ----
    v2f z[16];
    z[0].x = Fr; z[0].y = Fi;
#define EXPAND(Qi, M_)                                                    \
    {                                                                     \
        const v2f e0  = {ex_chcz[Qi], -ex_chsz[Qi]};                      \
        const v2f e0f = {ex_chsz[Qi],  ex_chcz[Qi]};                      \
        const v2f e1  = {ex_shcz[Qi],  ex_shsz[Qi]};                      \
        const v2f e1f = {-ex_shsz[Qi], ex_shcz[Qi]};                      \
        _Pragma("unroll")                                                 \
        for (int j = (M_) - 1; j >= 0; --j) {                             \
            const v2f a = z[j];                                           \
            z[2 * j + 1] = pk_fma_bl(a, e1, pk_mul_bh(a, e1f));           \
            z[2 * j]     = pk_fma_bl(a, e0, pk_mul_bh(a, e0f));           \
        }                                                                 \
    }
    EXPAND(0, 1)
    EXPAND(1, 2)
    EXPAND(2, 4)
    EXPAND(3, 8)
#undef EXPAND

    const int pv = __popc(L & 3) & 1;

    // ---- fused gates 0 & 7 (lane^15; g7 also r^1) — verified round 5:
    //   z'[r]   = K1 a + HG b + (±GC) c + (±HB) d
    //   z'[r+1] = HG a + K1 b - (±HB) c - (±GC) d      (± = (-1)^par(r))
    {
        const float c0 = c2q[0], s0 = s2q[0], c7 = c2q[7], s7 = s2q[7];
        const int pu = __popc(L & 11) & 1;
        const float G = pu ? s0 : -s0;
        const float H = pv ? s7 : -s7;
        const v2f K1p = {c7 * c0, c7 * c0};
        const v2f HGp = {H * G, H * G};
        const v2f GCp = {G * c7, G * c7};
        const v2f HBp = {H * c0, H * c0};
#pragma unroll
        for (int r = 0; r < 16; r += 2) {
            const bool ev = (__builtin_popcount(r) & 1) == 0;   // compile-time
            const v2f a = z[r], b = z[r + 1];
            const v2f c = dpp2<DPP_XOR15>(a);
            const v2f d = dpp2<DPP_XOR15>(b);
            v2f za = pk_fma(b, HGp, pk_mul(a, K1p));
            v2f zb = pk_fma(a, HGp, pk_mul(b, K1p));
            if (ev) {
                za = pk_fma(c, GCp, za);   za = pk_fma(d, HBp, za);
                zb = pk_fma_n(c, HBp, zb); zb = pk_fma_n(d, GCp, zb);
            } else {
                za = pk_fma_n(c, GCp, za); za = pk_fma_n(d, HBp, za);
                zb = pk_fma(c, HBp, zb);   zb = pk_fma(d, GCp, zb);
            }
            z[r] = za; z[r + 1] = zb;
        }
    }
    // ---- gate 1: lane^7; role par(u&12) ----
    {
        const float cc = c2q[1];
        const float g = (__popc(L & 12) & 1) ? s2q[1] : -s2q[1];
        const v2f ccp = {cc, cc}, gp = {g, g};
#pragma unroll
        for (int r = 0; r < 16; ++r) {
            const v2f o = dpp2<DPP_XOR7>(z[r]);
            z[r] = pk_fma(o, gp, pk_mul(z[r], ccp));
        }
    }
    // ---- gate 2: lane^3; role par(u&6) ----
    {
        const float cc = c2q[2];
        const float g = (__popc(L & 6) & 1) ? s2q[2] : -s2q[2];
        const v2f ccp = {cc, cc}, gp = {g, g};
#pragma unroll
        for (int r = 0; r < 16; ++r) {
            const v2f o = dpp2<DPP_XOR3>(z[r]);
            z[r] = pk_fma(o, gp, pk_mul(z[r], ccp));
        }
    }
    // ---- gate 3: lane^1 & r^8; role pv ----
    {
        const float cc = c2q[3];
        const float g = pv ? s2q[3] : -s2q[3];
        const v2f ccp = {cc, cc}, gp = {g, g};
#pragma unroll
        for (int r = 0; r < 8; ++r) {
            const v2f oA = dpp2<DPP_XOR1>(z[r + 8]);
            const v2f oB = dpp2<DPP_XOR1>(z[r]);
            z[r]     = pk_fma(oA, gp, pk_mul(z[r], ccp));
            z[r + 8] = pk_fma(oB, gp, pk_mul(z[r + 8], ccp));
        }
    }
    // ---- reg-local gates 4..6: pair r^MR; role pv ^ par(r&RR) ----
#define REGGATE(Q, MR, HBIT, RR)                                              \
    {                                                                         \
        const float cc = c2q[Q];                                              \
        const float g = pv ? s2q[Q] : -s2q[Q];                                \
        const v2f ccp = {cc, cc}, gp = {g, g};                                \
        _Pragma("unroll")                                                     \
        for (int r = 0; r < 16; ++r) {                                        \
            if ((r & (HBIT)) == 0) {                                          \
                const int rB = r ^ (MR);                                      \
                const bool pos = (__builtin_popcount(r & (RR)) & 1) == 0;     \
                const v2f a = z[r], b = z[rB];                                \
                if (pos) {                                                    \
                    z[r]  = pk_fma(b, gp, pk_mul(a, ccp));                    \
                    z[rB] = pk_fma_n(a, gp, pk_mul(b, ccp));                  \
                } else {                                                      \
                    z[r]  = pk_fma_n(b, gp, pk_mul(a, ccp));                  \
                    z[rB] = pk_fma(a, gp, pk_mul(b, ccp));                    \
                }                                                             \
            }                                                                 \
        }                                                                     \
    }
    REGGATE(4, 12, 8, 8)
    REGGATE(5, 6, 4, 12)
    REGGATE(6, 3, 2, 14)
#undef REGGATE

    // ---- packed measurement tree (hadd deferred to the 5 final sums) ----
    v2f Ph[8], Mh[8];
#pragma unroll
    for (int j = 0; j < 8; ++j) {
        const v2f a = pk_mul(z[2 * j], z[2 * j]);
        const v2f b = pk_mul(z[2 * j + 1], z[2 * j + 1]);
        Ph[j] = pk_add(a, b);
        Mh[j] = pk_sub(a, b);
    }
    v2f MPh[4], MMh[4], PMh[4];
#pragma unroll
    for (int i = 0; i < 4; ++i) {
        MPh[i] = pk_add(Mh[2 * i], Mh[2 * i + 1]);
        MMh[i] = pk_sub(Mh[2 * i], Mh[2 * i + 1]);
        PMh[i] = pk_sub(Ph[2 * i], Ph[2 * i + 1]);
    }
    const v2f MPM0 = pk_sub(MPh[0], MPh[1]), MPM1 = pk_sub(MPh[2], MPh[3]);
    const v2f MMM0 = pk_sub(MMh[0], MMh[1]), MMM1 = pk_sub(MMh[2], MMh[3]);
    const v2f MMP0 = pk_add(MMh[0], MMh[1]), MMP1 = pk_add(MMh[2], MMh[3]);
    const v2f PMP0 = pk_add(PMh[0], PMh[1]), PMP1 = pk_add(PMh[2], PMh[3]);
    const v2f S5h  = pk_add(MPM0, MPM1);
    const v2f S7h  = pk_add(MMM0, MMM1);
    const v2f S15h = pk_sub(MMM0, MMM1);
    const v2f S11h = pk_sub(MMP0, MMP1);
    const v2f S10h = pk_sub(PMP0, PMP1);
    const float S5  = S5h.x + S5h.y;
    const float S7  = S7h.x + S7h.y;
    const float S15 = S15h.x + S15h.y;
    const float S11 = S11h.x + S11h.y;
    const float S10 = S10h.x + S10h.y;

    // ---- lane sign prefactors; C_i lane masks: {9,7,1,2,1,2,1,2} ----
    const float sg1 = (L & 1) ? -1.f : 1.f;
    const float sg2 = (L & 2) ? -1.f : 1.f;
    const float sg9 = (__popc(L & 9) & 1) ? -1.f : 1.f;
    const float sg7 = (__popc(L & 7) & 1) ? -1.f : 1.f;
    float acc[8];
    acc[0] = sg9 * S5;
    acc[1] = sg7 * S15;
    acc[2] = sg1 * S15;
    acc[3] = sg2 * S15;
    acc[4] = sg1 * S7;
    acc[5] = sg2 * S11;
    acc[6] = sg1 * S5;
    acc[7] = sg2 * S10;

    // ---- transpose-reduce over 16 lanes (DPP); lane L<8 ends with sum of acc[L] ----
    const int h0 = L & 1, h1 = (L >> 1) & 1, h2 = (L >> 2) & 1;
    float t4a[4];
#pragma unroll
    for (int k = 0; k < 4; ++k) {
        const float send = h0 ? acc[2 * k] : acc[2 * k + 1];
        const float recv = dppf<DPP_XOR1>(send);
        t4a[k] = (h0 ? acc[2 * k + 1] : acc[2 * k]) + recv;
    }
    float t2a[2];
#pragma unroll
    for (int k = 0; k < 2; ++k) {
        const float send = h1 ? t4a[2 * k] : t4a[2 * k + 1];
        const float recv = dppf<DPP_XOR2>(send);
        t2a[k] = (h1 ? t4a[2 * k + 1] : t4a[2 * k]) + recv;
    }
    {
        const float send = h2 ? t2a[0] : t2a[1];
        const float recv = xor4f(send);
        float res = (h2 ? t2a[1] : t2a[0]) + recv;
        res += xor8f(res);   // fold the two u3-halves
        if (L < 8) out[(size_t)sample * 8 + L] = res;
    }
}

extern "C" void kernel_launch(void* const* d_in, const int* in_sizes, int n_in,
                              void* d_out, int out_size, void* d_ws, size_t ws_size,
                              hipStream_t stream) {
    const float* x = (const float*)d_in[0];
    const float* w = (const float*)d_in[1];
    float* outp = (float*)d_out;
    const int nsamples = in_sizes[0] / 8;
    const int nthreads = nsamples * 16;
    const int block = 256;
    const int grid = (nthreads + block - 1) / block;
    qsim8_kernel<<<grid, block, 0, stream>>>(x, w, outp, nsamples);
}

// Round 8
// 24.445 us; speedup vs baseline: 1.0090x; 1.0090x over previous
//
#include <hip/hip_runtime.h>

typedef float v2f __attribute__((ext_vector_type(2)));
typedef _Float16 h2v __attribute__((ext_vector_type(2)));

#define PI_OVER_4 0.78539816339744830962f

// ---- DPP lane permutes (VALU pipe) ----
#define DPP_XOR1  0xB1    // quad_perm [1,0,3,2]
#define DPP_XOR2  0x4E    // quad_perm [2,3,0,1]
#define DPP_XOR3  0x1B    // quad_perm [3,2,1,0]
#define DPP_XOR7  0x141   // row_half_mirror
#define DPP_XOR15 0x140   // row_mirror

template <int CTRL>
__device__ __forceinline__ float dppf(float v) {
    return __int_as_float(
        __builtin_amdgcn_update_dpp(0, __float_as_int(v), CTRL, 0xF, 0xF, true));
}
template <int CTRL>
__device__ __forceinline__ h2v dpph(h2v v) {
    int i = __builtin_bit_cast(int, v);
    i = __builtin_amdgcn_update_dpp(0, i, CTRL, 0xF, 0xF, true);
    return __builtin_bit_cast(h2v, i);
}
__device__ __forceinline__ float xor4f(float v) { return dppf<DPP_XOR3>(dppf<DPP_XOR7>(v)); }
__device__ __forceinline__ float xor8f(float v) { return dppf<DPP_XOR7>(dppf<DPP_XOR15>(v)); }

// ---- packed fp32 (VOP3P, half-rate — used only in the exact expansion) ----
__device__ __forceinline__ v2f pk_mul_bh(v2f a, v2f b) {       // (a.y,a.y) * b
    v2f d; asm("v_pk_mul_f32 %0, %1, %2 op_sel:[1,0] op_sel_hi:[1,1]" : "=v"(d) : "v"(a), "v"(b)); return d;
}
__device__ __forceinline__ v2f pk_fma_bl(v2f a, v2f b, v2f c) { // (a.x,a.x)*b + c
    v2f d; asm("v_pk_fma_f32 %0, %1, %2, %3 op_sel:[0,0,0] op_sel_hi:[0,1,1]" : "=v"(d) : "v"(a), "v"(b), "v"(c)); return d;
}

// ---- packed fp16 (VOP3P, FULL-rate: 2 elements / 2 cycles) ----
__device__ __forceinline__ h2v pkh_mul(h2v a, h2v b) {
    h2v d; asm("v_pk_mul_f16 %0, %1, %2" : "=v"(d) : "v"(a), "v"(b)); return d;
}
__device__ __forceinline__ h2v pkh_fma(h2v a, h2v b, h2v c) {
    h2v d; asm("v_pk_fma_f16 %0, %1, %2, %3" : "=v"(d) : "v"(a), "v"(b), "v"(c)); return d;
}
// |z|^2 accumulation with f16 inputs at f32 precision (v_fma_mix_f32)
__device__ __forceinline__ float fmamix_lo(h2v a, float c) {
    float d; asm("v_fma_mix_f32 %0, %1, %1, %2 op_sel_hi:[1,1,0]" : "=v"(d) : "v"(a), "v"(c)); return d;
}
__device__ __forceinline__ float fmamix_hi(h2v a, float c) {
    float d; asm("v_fma_mix_f32 %0, %1, %1, %2 op_sel:[1,1,0] op_sel_hi:[1,1,0]" : "=v"(d) : "v"(a), "v"(c)); return d;
}

__device__ __forceinline__ h2v h2f(float s) {
    _Float16 h = (_Float16)s; h2v r; r.x = h; r.y = h; return r;
}
__device__ __forceinline__ h2v cvt2h(v2f a) {
    return __builtin_bit_cast(h2v, __builtin_amdgcn_cvt_pkrtz(a.x, a.y));
}
__device__ __forceinline__ float bperm(int addr, float v) {
    return __int_as_float(__builtin_amdgcn_ds_bpermute(addr, __float_as_int(v)));
}

// 16 lanes/sample. Pre-L1-ring coords t (s = P t); reg r bits (3..0) = (t4..t7).
// Lane bits u (recode): u3=t0, u2=t1, u1=t0^t2, u0=t1^t3.
// Cross-lane gate masks: g0&g7: lane^15 (g7 also r^1); g1: lane^7; g2: lane^3;
// g3: lane^1 & r^8. Reg gates g4,g5,g6: r^12, r^6, r^3.
// Roles: s0=par(u&11)^par(r&15), s1=par(u&12), s2=par(u&6), s3=pv,
// s4..s7 = pv^par(r&{8,12,14,15}); pv=par(u&3).   [verified rounds 5/6]
__global__ __launch_bounds__(256, 5) void qsim8_kernel(
        const float* __restrict__ x, const float* __restrict__ w,
        float* __restrict__ out, int nsamples) {
    const int tid = blockIdx.x * blockDim.x + threadIdx.x;
    const int sample = tid >> 4;
    if (sample >= nsamples) return;
    const int lane = threadIdx.x & 63;
    const int L = lane & 15;
    const int q8 = L & 7;

    // ---- per-lane transcendentals (2 sincos/lane) ----
    const float xq = x[(size_t)sample * 8 + q8];
    const float wA = (L < 8) ? w[2 * q8] : w[16 + 2 * q8];
    const float wB = w[2 * q8 + 1];
    const float Aang = fmaf(xq, PI_OVER_4, 0.5f * wA);
    const float Bang = 0.5f * wB;
    float sA_, cA_, sB_, cB_;
    __sincosf(Aang, &sA_, &cA_);
    __sincosf(Bang, &sB_, &cB_);
    const float v_chcz = cA_ * cB_, v_chsz = cA_ * sB_;
    const float v_shcz = sA_ * cB_, v_shsz = sA_ * sB_;

    // ---- distribute coefficients within the 16-lane group ----
    const int base = (lane & 48) << 2;
    float lf_chcz[4], lf_chsz[4], lf_shcz[4], lf_shsz[4];
    float ex_chcz[4], ex_chsz[4], ex_shcz[4], ex_shsz[4];
    float c2q[8], s2q[8];
#pragma unroll
    for (int q = 0; q < 4; ++q) {
        const int ad = base + 4 * q;
        lf_chcz[q] = bperm(ad, v_chcz); lf_chsz[q] = bperm(ad, v_chsz);
        lf_shcz[q] = bperm(ad, v_shcz); lf_shsz[q] = bperm(ad, v_shsz);
    }
#pragma unroll
    for (int q = 0; q < 4; ++q) {
        const int ad = base + 4 * (4 + q);
        ex_chcz[q] = bperm(ad, v_chcz); ex_chsz[q] = bperm(ad, v_chsz);
        ex_shcz[q] = bperm(ad, v_shcz); ex_shsz[q] = bperm(ad, v_shsz);
    }
#pragma unroll
    for (int q = 0; q < 8; ++q) {
        const int ad = base + 4 * (8 + q);
        c2q[q] = bperm(ad, cA_); s2q[q] = bperm(ad, sA_);
    }

    // ---- lane factor: qubits 0..3 selected by t-bits of this lane ----
    const int b0 = (L >> 3) & 1;
    const int b1 = (L >> 2) & 1;
    const int b2 = ((L >> 1) ^ (L >> 3)) & 1;
    const int b3 = (L ^ (L >> 2)) & 1;
    float Fr = b0 ? lf_shcz[0] : lf_chcz[0];
    float Fi = b0 ? lf_shsz[0] : -lf_chsz[0];
    {
        const float g1r = b1 ? lf_shcz[1] : lf_chcz[1];
        const float g1i = b1 ? lf_shsz[1] : -lf_chsz[1];
        const float tr = Fr * g1r - Fi * g1i;
        const float ti = Fr * g1i + Fi * g1r;
        const float g2r = b2 ? lf_shcz[2] : lf_chcz[2];
        const float g2i = b2 ? lf_shsz[2] : -lf_chsz[2];
        const float ur = tr * g2r - ti * g2i;
        const float ui = tr * g2i + ti * g2r;
        const float g3r = b3 ? lf_shcz[3] : lf_chcz[3];
        const float g3i = b3 ? lf_shsz[3] : -lf_chsz[3];
        Fr = ur * g3r - ui * g3i;
        Fi = ur * g3i + ui * g3r;
    }

    // ---- expand product state over qubits 4..7 (exact fp32) ----
    v2f zf[16];
    zf[0].x = Fr; zf[0].y = Fi;
#define EXPAND(Qi, M_)                                                    \
    {                                                                     \
        const v2f e0  = {ex_chcz[Qi], -ex_chsz[Qi]};                      \
        const v2f e0f = {ex_chsz[Qi],  ex_chcz[Qi]};                      \
        const v2f e1  = {ex_shcz[Qi],  ex_shsz[Qi]};                      \
        const v2f e1f = {-ex_shsz[Qi], ex_shcz[Qi]};                      \
        _Pragma("unroll")                                                 \
        for (int j = (M_) - 1; j >= 0; --j) {                             \
            const v2f a = zf[j];                                          \
            zf[2 * j + 1] = pk_fma_bl(a, e1, pk_mul_bh(a, e1f));          \
            zf[2 * j]     = pk_fma_bl(a, e0, pk_mul_bh(a, e0f));          \
        }                                                                 \
    }
    EXPAND(0, 1)
    EXPAND(1, 2)
    EXPAND(2, 4)
    EXPAND(3, 8)
#undef EXPAND

    // ---- convert state to packed f16 (re,im in one VGPR) ----
    h2v z[16];
#pragma unroll
    for (int r = 0; r < 16; ++r) z[r] = cvt2h(zf[r]);

    const int pv = __popc(L & 3) & 1;

    // ---- fused gates 0 & 7 (lane^15; g7 also r^1) — verified round 5:
    //   z'[r]   = K1 a + HG b + (±GC) c + (±HB) d
    //   z'[r+1] = HG a + K1 b - (±HB) c - (±GC) d      (± = (-1)^par(r))
    {
        const float c0 = c2q[0], s0 = s2q[0], c7 = c2q[7], s7 = s2q[7];
        const int pu = __popc(L & 11) & 1;
        const float G = pu ? s0 : -s0;
        const float H = pv ? s7 : -s7;
        const h2v K1p = h2f(c7 * c0);
        const h2v HGp = h2f(H * G);
        const h2v GCp = h2f(G * c7), GCn = h2f(-(G * c7));
        const h2v HBp = h2f(H * c0), HBn = h2f(-(H * c0));
#pragma unroll
        for (int r = 0; r < 16; r += 2) {
            const bool ev = (__builtin_popcount(r) & 1) == 0;   // compile-time
            const h2v gc = ev ? GCp : GCn;
            const h2v hb = ev ? HBp : HBn;
            const h2v ngc = ev ? GCn : GCp;
            const h2v nhb = ev ? HBn : HBp;
            const h2v a = z[r], b = z[r + 1];
            const h2v c = dpph<DPP_XOR15>(a);
            const h2v d = dpph<DPP_XOR15>(b);
            h2v za = pkh_fma(b, HGp, pkh_mul(a, K1p));
            h2v zb = pkh_fma(a, HGp, pkh_mul(b, K1p));
            za = pkh_fma(c, gc, za);  za = pkh_fma(d, hb, za);
            zb = pkh_fma(c, nhb, zb); zb = pkh_fma(d, ngc, zb);
            z[r] = za; z[r + 1] = zb;
        }
    }
    // ---- gate 1: lane^7; role par(u&12) ----
    {
        const h2v ccp = h2f(c2q[1]);
        const h2v gp = h2f((__popc(L & 12) & 1) ? s2q[1] : -s2q[1]);
#pragma unroll
        for (int r = 0; r < 16; ++r) {
            const h2v o = dpph<DPP_XOR7>(z[r]);
            z[r] = pkh_fma(o, gp, pkh_mul(z[r], ccp));
        }
    }
    // ---- gate 2: lane^3; role par(u&6) ----
    {
        const h2v ccp = h2f(c2q[2]);
        const h2v gp = h2f((__popc(L & 6) & 1) ? s2q[2] : -s2q[2]);
#pragma unroll
        for (int r = 0; r < 16; ++r) {
            const h2v o = dpph<DPP_XOR3>(z[r]);
            z[r] = pkh_fma(o, gp, pkh_mul(z[r], ccp));
        }
    }
    // ---- gate 3: lane^1 & r^8; role pv ----
    {
        const h2v ccp = h2f(c2q[3]);
        const h2v gp = h2f(pv ? s2q[3] : -s2q[3]);
#pragma unroll
        for (int r = 0; r < 8; ++r) {
            const h2v oA = dpph<DPP_XOR1>(z[r + 8]);
            const h2v oB = dpph<DPP_XOR1>(z[r]);
            z[r]     = pkh_fma(oA, gp, pkh_mul(z[r], ccp));
            z[r + 8] = pkh_fma(oB, gp, pkh_mul(z[r + 8], ccp));
        }
    }
    // ---- reg-local gates 4..6: pair r^MR; role pv ^ par(r&RR) ----
#define REGGATE(Q, MR, HBIT, RR)                                              \
    {                                                                         \
        const float gbase = pv ? s2q[Q] : -s2q[Q];                            \
        const h2v ccp = h2f(c2q[Q]);                                          \
        const h2v gp = h2f(gbase), gn = h2f(-gbase);                          \
        _Pragma("unroll")                                                     \
        for (int r = 0; r < 16; ++r) {                                        \
            if ((r & (HBIT)) == 0) {                                          \
                const int rB = r ^ (MR);                                      \
                const bool pos = (__builtin_popcount(r & (RR)) & 1) == 0;     \
                const h2v s1 = pos ? gp : gn;                                 \
                const h2v s2 = pos ? gn : gp;                                 \
                const h2v a = z[r], b = z[rB];                                \
                z[r]  = pkh_fma(b, s1, pkh_mul(a, ccp));                      \
                z[rB] = pkh_fma(a, s2, pkh_mul(b, ccp));                      \
            }                                                                 \
        }                                                                     \
    }
    REGGATE(4, 12, 8, 8)
    REGGATE(5, 6, 4, 12)
    REGGATE(6, 3, 2, 14)
#undef REGGATE

    // ---- probabilities: f16 inputs, f32 multiply+accumulate (v_fma_mix) ----
    float p[16];
#pragma unroll
    for (int r = 0; r < 16; ++r)
        p[r] = fmamix_hi(z[r], fmamix_lo(z[r], 0.0f));

    // ---- 5 masked register sums S_m, m in {5,7,10,11,15} (fp32 shared trees) ----
    float P[8], M[8];
#pragma unroll
    for (int j = 0; j < 8; ++j) {
        P[j] = p[2 * j] + p[2 * j + 1];
        M[j] = p[2 * j] - p[2 * j + 1];
    }
    float MP[4], MM[4], PM[4];
#pragma unroll
    for (int i = 0; i < 4; ++i) {
        MP[i] = M[2 * i] + M[2 * i + 1];
        MM[i] = M[2 * i] - M[2 * i + 1];
        PM[i] = P[2 * i] - P[2 * i + 1];
    }
    const float MPM0 = MP[0] - MP[1], MPM1 = MP[2] - MP[3];
    const float MMM0 = MM[0] - MM[1], MMM1 = MM[2] - MM[3];
    const float MMP0 = MM[0] + MM[1], MMP1 = MM[2] + MM[3];
    const float PMP0 = PM[0] + PM[1], PMP1 = PM[2] + PM[3];
    const float S5  = MPM0 + MPM1;
    const float S7  = MMM0 + MMM1;
    const float S15 = MMM0 - MMM1;
    const float S11 = MMP0 - MMP1;
    const float S10 = PMP0 - PMP1;

    // ---- lane sign prefactors; C_i lane masks: {9,7,1,2,1,2,1,2} ----
    const float sg1 = (L & 1) ? -1.f : 1.f;
    const float sg2 = (L & 2) ? -1.f : 1.f;
    const float sg9 = (__popc(L & 9) & 1) ? -1.f : 1.f;
    const float sg7 = (__popc(L & 7) & 1) ? -1.f : 1.f;
    float acc[8];
    acc[0] = sg9 * S5;
    acc[1] = sg7 * S15;
    acc[2] = sg1 * S15;
    acc[3] = sg2 * S15;
    acc[4] = sg1 * S7;
    acc[5] = sg2 * S11;
    acc[6] = sg1 * S5;
    acc[7] = sg2 * S10;

    // ---- transpose-reduce over 16 lanes (DPP); lane L<8 ends with sum of acc[L] ----
    const int h0 = L & 1, h1 = (L >> 1) & 1, h2 = (L >> 2) & 1;
    float t4a[4];
#pragma unroll
    for (int k = 0; k < 4; ++k) {
        const float send = h0 ? acc[2 * k] : acc[2 * k + 1];
        const float recv = dppf<DPP_XOR1>(send);
        t4a[k] = (h0 ? acc[2 * k + 1] : acc[2 * k]) + recv;
    }
    float t2a[2];
#pragma unroll
    for (int k = 0; k < 2; ++k) {
        const float send = h1 ? t4a[2 * k] : t4a[2 * k + 1];
        const float recv = dppf<DPP_XOR2>(send);
        t2a[k] = (h1 ? t4a[2 * k + 1] : t4a[2 * k]) + recv;
    }
    {
        const float send = h2 ? t2a[0] : t2a[1];
        const float recv = xor4f(send);
        float res = (h2 ? t2a[1] : t2a[0]) + recv;
        res += xor8f(res);   // fold the two u3-halves
        if (L < 8) out[(size_t)sample * 8 + L] = res;
    }
}

extern "C" void kernel_launch(void* const* d_in, const int* in_sizes, int n_in,
                              void* d_out, int out_size, void* d_ws, size_t ws_size,
                              hipStream_t stream) {
    const float* x = (const float*)d_in[0];
    const float* w = (const float*)d_in[1];
    float* outp = (float*)d_out;
    const int nsamples = in_sizes[0] / 8;
    const int nthreads = nsamples * 16;
    const int block = 256;
    const int grid = (nthreads + block - 1) / block;
    qsim8_kernel<<<grid, block, 0, stream>>>(x, w, outp, nsamples);
}